// Round 1
// baseline (244.769 us; speedup 1.0000x reference)
//
#include <hip/hip_runtime.h>
#include <math.h>

// Dims (hard-coded per reference setup_inputs)
#define NN 64
#define CIN 64
#define COUT 64
#define TT 256
#define VV 17
#define NSUB 3
#define GG 8
#define TC 8              // timesteps per block in pass 1
#define NCHUNK (TT / TC)  // 32
// ws layout (floats)
#define OFF_M 0        // padded M: [3][8][17][20] = 8160
#define OFF_PSUM 8160  // [64][64]
#define OFF_SSQ 12256  // [64][64]
#define OFF_A 16352    // [64][64]
#define OFF_B 20448    // [64][64]

// ---------------- Kernel A: build M = A_base + DA + DAM*mask + 0.04 (padded), zero accumulators ----------------
__global__ void gcn_prep(const float* __restrict__ Ab, const float* __restrict__ DA,
                         const float* __restrict__ DAM, float* __restrict__ ws) {
    int tid = threadIdx.x;
    for (int i = tid; i < 8192; i += 256) ws[OFF_PSUM + i] = 0.f;  // psum+ssq
    const unsigned bad = (1u << 3) | (1u << 6) | (1u << 7) | (1u << 9) | (1u << 10);
    for (int idx = tid; idx < NSUB * GG * VV * 20; idx += 256) {
        int w = idx % 20;
        int tmp = idx / 20;
        int v = tmp % VV; tmp /= VV;
        int g = tmp & 7;
        int s = tmp >> 3;
        float val = 0.f;
        if (w < VV) {
            int src = ((s * GG + g) * VV + v) * VV + w;
            float mask = ((v >= 12 && w >= 12) || ((bad >> v) & 1) || ((bad >> w) & 1)) ? 0.f : 1.f;
            val = Ab[(s * VV + v) * VV + w] + DA[src] + DAM[src] * mask + 0.04f;
        }
        ws[OFF_M + idx] = val;
    }
}

// ---------------- Kernel B: fused 1x1 conv + adjacency, write m2 to d_out, accumulate psum/ssq ----------------
__global__ __launch_bounds__(512) void gcn_pass1(const float* __restrict__ x,
                                                 const float* __restrict__ convw,
                                                 const float* __restrict__ convb,
                                                 const float* __restrict__ ws,
                                                 float* __restrict__ m2out,
                                                 float* __restrict__ psum,
                                                 float* __restrict__ ssq) {
    __shared__ float xs[CIN * TC * 20];      // [ci][t][20] : 10240 f
    __shared__ float Wsh[192 * 65];          // [k][ci] padded : 12480 f
    __shared__ float Msh[NSUB * GG * VV * 20];  // 8160 f

    const int bid = blockIdx.x;
    const int n = bid >> 5;
    const int t0 = (bid & 31) * TC;
    const int tid = threadIdx.x;

    // stage x tile: coalesced 136-float runs per ci
    const float* xbase = x + (size_t)n * CIN * TT * VV + t0 * VV;
    for (int idx = tid; idx < CIN * TC * VV; idx += 512) {
        int ci = idx / (TC * VV);
        int rem = idx % (TC * VV);
        int t = rem / VV, v = rem % VV;
        xs[(ci * TC + t) * 20 + v] = xbase[ci * TT * VV + rem];
    }
    // stage W (transposed-pad layout [k][65])
    for (int idx = tid; idx < 192 * 64; idx += 512) {
        int k = idx >> 6, ci = idx & 63;
        Wsh[k * 65 + ci] = convw[idx];
    }
    // stage M
    for (int idx = tid; idx < NSUB * GG * VV * 20; idx += 512) Msh[idx] = ws[OFF_M + idx];
    __syncthreads();

    // wave = fixed g; lanes = 8 co x 8 t
    const int g = tid >> 6;
    const int lane = tid & 63;
    const int coIdx = lane >> 3;
    const int t = lane & 7;
    const int co = coIdx * 8 + g;  // co % 8 == g

    // conv: vals[s][v] = conv_b[s*64+co] + sum_ci x[ci][t][v] * W[s*64+co][ci]
    float vals[NSUB * VV];
    {
        float b0 = convb[co], b1 = convb[64 + co], b2 = convb[128 + co];
#pragma unroll
        for (int v = 0; v < VV; ++v) { vals[v] = b0; vals[17 + v] = b1; vals[34 + v] = b2; }
    }
    const int w0i = (0 * 64 + co) * 65, w1i = (1 * 64 + co) * 65, w2i = (2 * 64 + co) * 65;
#pragma unroll 4
    for (int ci = 0; ci < CIN; ++ci) {
        const float* xr = &xs[(ci * TC + t) * 20];
        float4 xa = *(const float4*)(xr);
        float4 xb = *(const float4*)(xr + 4);
        float4 xc = *(const float4*)(xr + 8);
        float4 xd = *(const float4*)(xr + 12);
        float xv[VV] = {xa.x, xa.y, xa.z, xa.w, xb.x, xb.y, xb.z, xb.w,
                        xc.x, xc.y, xc.z, xc.w, xd.x, xd.y, xd.z, xd.w, xr[16]};
        float w0 = Wsh[w0i + ci];
        float w1 = Wsh[w1i + ci];
        float w2 = Wsh[w2i + ci];
#pragma unroll
        for (int v = 0; v < VV; ++v) {
            vals[v] = fmaf(w0, xv[v], vals[v]);
            vals[17 + v] = fmaf(w1, xv[v], vals[17 + v]);
            vals[34 + v] = fmaf(w2, xv[v], vals[34 + v]);
        }
    }

    // adjacency: acc[w] = sum_{s,v} vals[s][v] * M[s][g][v][w]   (M reads wave-uniform)
    float acc[VV];
#pragma unroll
    for (int w = 0; w < VV; ++w) acc[w] = 0.f;
#pragma unroll
    for (int s = 0; s < NSUB; ++s) {
#pragma unroll
        for (int v = 0; v < VV; ++v) {
            float a = vals[s * VV + v];
            const float* mrow = &Msh[((s * GG + g) * VV + v) * 20];
            float4 m0 = *(const float4*)(mrow);
            float4 m1 = *(const float4*)(mrow + 4);
            float4 m2v = *(const float4*)(mrow + 8);
            float4 m3 = *(const float4*)(mrow + 12);
            float mv[VV] = {m0.x, m0.y, m0.z, m0.w, m1.x, m1.y, m1.z, m1.w,
                            m2v.x, m2v.y, m2v.z, m2v.w, m3.x, m3.y, m3.z, m3.w, mrow[16]};
#pragma unroll
            for (int w = 0; w < VV; ++w) acc[w] = fmaf(a, mv[w], acc[w]);
        }
    }

    // store m2 + accumulate stats
    float s1 = 0.f, s2 = 0.f;
    float* obase = m2out + (((size_t)n * COUT + co) * TT + t0 + t) * VV;
#pragma unroll
    for (int w = 0; w < VV; ++w) {
        float o = acc[w];
        obase[w] = o;
        s1 += o;
        s2 += o * o;
    }
    // reduce across the 8 t-lanes (same co)
    s1 += __shfl_down(s1, 4, 8); s2 += __shfl_down(s2, 4, 8);
    s1 += __shfl_down(s1, 2, 8); s2 += __shfl_down(s2, 2, 8);
    s1 += __shfl_down(s1, 1, 8); s2 += __shfl_down(s2, 1, 8);
    if (t == 0) {
        atomicAdd(&psum[n * 64 + co], s1);
        atomicAdd(&ssq[n * 64 + co], s2);
    }
}

// ---------------- Kernel C: SE gate + BN stats -> per-(n,c) affine coefs ----------------
__global__ void gcn_stats(const float* __restrict__ se_w, const float* __restrict__ gamma,
                          const float* __restrict__ beta, float* __restrict__ ws) {
    __shared__ float ps[4096], sc[4096], q2s[4096];
    __shared__ float mu_s[64], inv_s[64];
    int tid = threadIdx.x;
    const float* psum = ws + OFF_PSUM;
    const float* ssq = ws + OFF_SSQ;
    float* acoef = ws + OFF_A;
    float* bcoef = ws + OFF_B;
    for (int i = tid; i < 4096; i += 256) ps[i] = psum[i] * (1.f / (TT * VV));
    __syncthreads();
    float w0 = se_w[0], w1 = se_w[1], w2 = se_w[2];
    for (int i = tid; i < 4096; i += 256) {
        int c = i & 63;
        float pm = (c > 0) ? ps[i - 1] : 0.f;
        float pp = (c < 63) ? ps[i + 1] : 0.f;
        float gg = w0 * pm + w1 * ps[i] + w2 * pp;
        float s = 1.f + 1.f / (1.f + expf(-gg));
        sc[i] = s;
        q2s[i] = s * s * ssq[i];
    }
    __syncthreads();
    if (tid < 64) {
        float mu = 0.f, e2 = 0.f;
        for (int nn = 0; nn < 64; ++nn) {
            mu += sc[nn * 64 + tid] * ps[nn * 64 + tid];
            e2 += q2s[nn * 64 + tid];
        }
        mu *= (1.f / 64.f);
        e2 *= (1.f / (64.f * TT * VV));
        float var = e2 - mu * mu;
        mu_s[tid] = mu;
        inv_s[tid] = rsqrtf(var + 1e-5f);
    }
    __syncthreads();
    for (int i = tid; i < 4096; i += 256) {
        int c = i & 63;
        float gin = gamma[c] * inv_s[c];
        acoef[i] = gin * sc[i];
        bcoef[i] = beta[c] - gin * mu_s[c];
    }
}

// ---------------- Kernel D: out = relu(a*m2 + b + x), in-place on d_out ----------------
__global__ __launch_bounds__(256) void gcn_final(const float* __restrict__ x,
                                                 const float* __restrict__ ws,
                                                 float* __restrict__ out) {
    const float* acoef = ws + OFF_A;
    const float* bcoef = ws + OFF_B;
    int i = blockIdx.x * 256 + threadIdx.x;
    const int total4 = (NN * COUT * TT * VV) / 4;  // 4,456,448
    if (i >= total4) return;
    int nc = i / ((TT * VV) / 4);  // 1088 float4 per (n,c)
    float a = acoef[nc], b = bcoef[nc];
    float4 m = ((const float4*)out)[i];
    float4 xx = ((const float4*)x)[i];
    float4 r;
    r.x = fmaxf(fmaf(a, m.x, b) + xx.x, 0.f);
    r.y = fmaxf(fmaf(a, m.y, b) + xx.y, 0.f);
    r.z = fmaxf(fmaf(a, m.z, b) + xx.z, 0.f);
    r.w = fmaxf(fmaf(a, m.w, b) + xx.w, 0.f);
    ((float4*)out)[i] = r;
}

extern "C" void kernel_launch(void* const* d_in, const int* in_sizes, int n_in,
                              void* d_out, int out_size, void* d_ws, size_t ws_size,
                              hipStream_t stream) {
    const float* x = (const float*)d_in[0];
    const float* Ab = (const float*)d_in[1];
    const float* DA = (const float*)d_in[2];
    const float* DAM = (const float*)d_in[3];
    const float* convw = (const float*)d_in[4];
    const float* convb = (const float*)d_in[5];
    const float* sew = (const float*)d_in[6];
    const float* gamma = (const float*)d_in[7];
    const float* beta = (const float*)d_in[8];
    float* out = (float*)d_out;
    float* ws = (float*)d_ws;

    gcn_prep<<<1, 256, 0, stream>>>(Ab, DA, DAM, ws);
    gcn_pass1<<<NN * NCHUNK, 512, 0, stream>>>(x, convw, convb, ws, out,
                                               ws + OFF_PSUM, ws + OFF_SSQ);
    gcn_stats<<<1, 256, 0, stream>>>(sew, gamma, beta, ws);
    const int total4 = (NN * COUT * TT * VV) / 4;
    gcn_final<<<(total4 + 255) / 256, 256, 0, stream>>>(x, ws, out);
}